// Round 2
// baseline (116.887 us; speedup 1.0000x reference)
//
#include <hip/hip_runtime.h>
#include <stdint.h>

#define BN 4096
#define DK 512
#define THRESH 0.5f
#define MARGIN 0.1f

typedef __attribute__((ext_vector_type(4)))  int   i32x4;
typedef __attribute__((ext_vector_type(8)))  int   i32x8;
typedef __attribute__((ext_vector_type(16))) float f32x16;
typedef __attribute__((ext_vector_type(8))) unsigned short ushort8;
typedef __attribute__((ext_vector_type(2))) unsigned long long ulong2_t;

__device__ __forceinline__ unsigned short f2bf(float f) {
    unsigned u = __float_as_uint(f);
    u += 0x7FFFu + ((u >> 16) & 1u);   // RNE
    return (unsigned short)(u >> 16);
}
__device__ __forceinline__ float bf2f(unsigned short b) {
    return __uint_as_float((unsigned)b << 16);
}

// fp32 -> OCP e4m3fn, RNE (software; inputs here are |x| <~ 0.5 so the
// clamp/NaN paths are never hot). Subnormal: m = round(a * 2^9).
__device__ __forceinline__ unsigned char f2fp8(float x) {
    float a = fabsf(x);
    unsigned s = (__float_as_uint(x) >> 24) & 0x80u;
    if (a >= 448.f) return (unsigned char)(s | 0x7E);      // clamp to max finite
    if (a < 0.015625f) {                                    // < 2^-6: subnormal
        int m = (int)(a * 512.0f + 0.5f);                   // 0..8 (8 == 2^-6 normal)
        return (unsigned char)(s | m);
    }
    unsigned u = __float_as_uint(a);
    u += 0x0FFFFFu + ((u >> 20) & 1u);                      // RNE into 3-bit mantissa
    unsigned e = (u >> 23) - 127u + 7u;
    unsigned m = (u >> 20) & 7u;
    if (e >= 16u) return (unsigned char)(s | 0x7E);
    return (unsigned char)(s | (e << 3) | m);
}

// feats fp32 -> fp8 e4m3 (for MFMA); block 0 thread 0 zero-inits out[0]
// (harness re-poisons d_out to 0xAA before every timed replay).
__global__ void cvt_kernel(const float4* __restrict__ in, uchar4* __restrict__ out,
                           float* __restrict__ loss_out) {
    int i = blockIdx.x * blockDim.x + threadIdx.x;   // 524288 threads, 4 elems each
    float4 v = in[i];
    uchar4 o;
    o.x = f2fp8(v.x); o.y = f2fp8(v.y); o.z = f2fp8(v.z); o.w = f2fp8(v.w);
    out[i] = o;
    if (blockIdx.x == 0 && threadIdx.x == 0) loss_out[0] = 0.f;
}

// Triangular GEMM, fp8 inputs: sim = F8 @ F8^T (fp32 accumulate), bf16 store.
// Only the 528 upper-triangle 128x128 tiles are computed; off-diagonal blocks
// mirror-store C^T via an LDS round-trip.
//
// NO LDS STAGING: Fb is 2 MB -> resident in every XCD's 4 MiB L2 after first
// touch (Common-mistake #7: staging L2-fit data is pure overhead). MFMA
// fragments are read DIRECTLY from global/L2. This removes the entire
// 4x (stage + vmcnt(0)-drain + 2 barriers) K-pipeline.
//
// MFMA shape: mfma_scale_f32_32x32x64_f8f6f4 with both scales = 0x7F (E8M0
// 2^0) == exact fp8 matmul at 2x the 16x16x32 rate. Chosen because its A/B
// fragment is 32 CONSECUTIVE k-bytes per lane (lane&31 = row/col, lane>>5 =
// k-half), so the direct-global fragment load is 2x global_load_dwordx4 with
// 64B-line-perfect coalescing (32 rows x 64 B contiguous per wave).
// Each wave owns a 64x64 quadrant = 2x2 MFMAs of 32x32, acc 16 f32 each.
__global__ __launch_bounds__(256, 4) void ms_gemm(
    const unsigned char* __restrict__ Fb,   // fp8 e4m3 [4096][512] row-major
    unsigned short* __restrict__ simb)      // bf16 bits [4096][4096]
{
    __shared__ __align__(16) unsigned short SMEM[128 * 128];  // 32 KB mirror buf

    const int t    = threadIdx.x;
    const int lane = t & 63;
    const int w    = t >> 6;
    const int wr   = w >> 1, wc = w & 1;
    const int l31  = lane & 31;
    const int kh   = lane >> 5;          // k-half within K=64

    // map linear block id -> upper-triangle tile (by <= bx), 528 blocks
    int l = blockIdx.x, by = 0;
    while (l >= 32 - by) { l -= (32 - by); ++by; }
    const int bx = by + l;
    const int rowBase = by * 128;
    const int colBase = bx * 128;
    const bool diag = (by == bx);

    // Per-lane global fragment pointers (L2-resident). A: row panel, B: col panel.
    const unsigned char* aP[2];
    const unsigned char* bP[2];
#pragma unroll
    for (int im = 0; im < 2; ++im)
        aP[im] = Fb + (size_t)(rowBase + wr * 64 + im * 32 + l31) * DK + kh * 32;
#pragma unroll
    for (int jn = 0; jn < 2; ++jn)
        bP[jn] = Fb + (size_t)(colBase + wc * 64 + jn * 32 + l31) * DK + kh * 32;

    f32x16 acc[2][2];
#pragma unroll
    for (int i = 0; i < 2; ++i)
#pragma unroll
        for (int j = 0; j < 2; ++j)
#pragma unroll
            for (int e = 0; e < 16; ++e) acc[i][j][e] = 0.f;

#pragma unroll
    for (int ks = 0; ks < 8; ++ks) {     // K = ks*64, fully unrolled; compiler
        i32x8 af[2], bg[2];              // pipelines the 8 loads over the MFMAs
#pragma unroll
        for (int im = 0; im < 2; ++im) {
            i32x4 lo = *reinterpret_cast<const i32x4*>(aP[im] + ks * 64);
            i32x4 hi = *reinterpret_cast<const i32x4*>(aP[im] + ks * 64 + 16);
            af[im] = __builtin_shufflevector(lo, hi, 0, 1, 2, 3, 4, 5, 6, 7);
        }
#pragma unroll
        for (int jn = 0; jn < 2; ++jn) {
            i32x4 lo = *reinterpret_cast<const i32x4*>(bP[jn] + ks * 64);
            i32x4 hi = *reinterpret_cast<const i32x4*>(bP[jn] + ks * 64 + 16);
            bg[jn] = __builtin_shufflevector(lo, hi, 0, 1, 2, 3, 4, 5, 6, 7);
        }
#pragma unroll
        for (int im = 0; im < 2; ++im)
#pragma unroll
            for (int jn = 0; jn < 2; ++jn)
                acc[im][jn] = __builtin_amdgcn_mfma_scale_f32_32x32x64_f8f6f4(
                    af[im], bg[jn], acc[im][jn],
                    0, 0,                       // cbsz=FP8(e4m3), blgp=FP8(e4m3)
                    0, 0x7F7F7F7F,              // scale A = 2^0 (exact)
                    0, 0x7F7F7F7F);             // scale B = 2^0 (exact)
    }

    // Direct store. C/D layout (32x32): col=lane&31, row=(reg&3)+8*(reg>>2)+4*kh.
#pragma unroll
    for (int im = 0; im < 2; ++im)
#pragma unroll
        for (int g = 0; g < 4; ++g)
#pragma unroll
            for (int rg = 0; rg < 4; ++rg) {
                const int grow = rowBase + wr * 64 + im * 32 + g * 8 + kh * 4 + rg;
                unsigned short* dst = simb + (size_t)grow * BN + colBase + wc * 64 + l31;
#pragma unroll
                for (int jn = 0; jn < 2; ++jn)
                    dst[jn * 32] = f2bf(acc[im][jn][g * 4 + rg]);
            }

    if (diag) return;

    // Mirror store: write C^T into SMEM (phys 16B-chunk XOR-swizzled by column),
    // then read rows of C^T and store 16B-coalesced to sim[col][row].
    // acc regs g*4+0..3 are rows r..r+3 (r = im*32+g*8+kh*4, so r&7 in {0,4}).
    __syncthreads();   // harmless; keeps SMEM use ordered across epilogue phases
#pragma unroll
    for (int im = 0; im < 2; ++im)
#pragma unroll
        for (int jn = 0; jn < 2; ++jn)
#pragma unroll
            for (int g = 0; g < 4; ++g) {
                ushort4 v;
                v.x = f2bf(acc[im][jn][g * 4 + 0]);
                v.y = f2bf(acc[im][jn][g * 4 + 1]);
                v.z = f2bf(acc[im][jn][g * 4 + 2]);
                v.w = f2bf(acc[im][jn][g * 4 + 3]);
                const int c  = wc * 64 + jn * 32 + l31;            // tile col
                const int r  = wr * 64 + im * 32 + g * 8 + kh * 4; // tile row
                const int r8 = r >> 3;                             // 16B chunk 0..15
                const int ri = r & 7;                              // 0 or 4
                *reinterpret_cast<ushort4*>(
                    &SMEM[c * 128 + ((r8 ^ (c & 15)) << 3) + ri]) = v;
            }
    __syncthreads();

    const int lch = t & 7;    // low 16B chunk of the transposed row
    const int trw = t >> 3;   // 0..31
#pragma unroll
    for (int it = 0; it < 4; ++it) {
        const int tr = it * 32 + trw;                      // transposed row = orig col
        const int q1 = lch ^ (tr & 15);
        const int q2 = (lch + 8) ^ (tr & 15);
        ushort8 a = *reinterpret_cast<const ushort8*>(&SMEM[tr * 128 + q1 * 8]);
        ushort8 b = *reinterpret_cast<const ushort8*>(&SMEM[tr * 128 + q2 * 8]);
        unsigned short* dst = simb + (size_t)(colBase + tr) * BN + rowBase;
        *reinterpret_cast<ushort8*>(&dst[lch * 8])       = a;
        *reinterpret_cast<ushort8*>(&dst[(lch + 8) * 8]) = b;
    }
}

// Per-row pass: one wave owns one full row (held in 32 VGPRs), so the row's
// min/max thresholds are wave-local. 1024 blocks x 4 waves x 1 row.
// Labels staged transposed in LDS (conflict-free per-(j,e) reads).
//
// Pass 1 builds, per lane: running min over pos / max over neg, plus two
// 64-bit candidate masks: mpos (pos pairs) and mneg (!same && s > 0.125 —
// the numeric neg cutoff; dropped terms are each < e^-15, Dloss <= 3.1e-5).
// Pass 2 walks ONLY the set bits (~8 pos + ~10 hot-neg per ROW) instead of a
// dense 64-iteration scan. Validity is wave-uniform: exists neg with
// s+M > tP <=> hasNeg && mx+M > tP (mx exact max over ALL negs); same for pos.
__global__ __launch_bounds__(256) void ms_rows(
    const unsigned short* __restrict__ simb,
    const int* __restrict__ labels,
    const int* __restrict__ label_num,
    float* __restrict__ out)
{
    __shared__ int   labT[8][512];   // 16 KB, labT[i&7][i>>3] = labels[i]
    __shared__ float bsum[4];

    const int t    = threadIdx.x;
    const int lane = t & 63;
    const int w    = t >> 6;

    for (int i = t; i < BN; i += 256) labT[i & 7][i >> 3] = labels[i];
    __syncthreads();

    const int lim = BN - label_num[0];
    const int row = blockIdx.x * 4 + w;
    const int lr  = labT[row & 7][row >> 3];
    const ulong2_t* rq = (const ulong2_t*)(simb + (size_t)row * BN);

    ulong2_t q[8];                    // full row: 8 x 16B per lane (32 VGPRs)
    uint64_t mpos = 0, mneg = 0;
    float mn = INFINITY, mx = -INFINITY;
#pragma unroll
    for (int j = 0; j < 8; ++j) {
        q[j] = rq[j * 64 + lane];
        const int c8 = j * 64 + lane;            // col>>3 for this lane's 8 elems
#pragma unroll
        for (int e = 0; e < 8; ++e) {
            const int col = c8 * 8 + e;
            const float s = bf2f((unsigned short)(q[j][e >> 2] >> ((e & 3) * 16)));
            const bool same = (labT[e][c8] == lr);   // conflict-free LDS read
            const bool pos  = same && (col != row);
            if (pos)   mn = fminf(mn, s);
            if (!same) mx = fmaxf(mx, s);
            mpos |= (uint64_t)pos << (j * 8 + e);
            mneg |= (uint64_t)(!same && (s > 0.125f)) << (j * 8 + e);
        }
    }
#pragma unroll
    for (int off = 1; off < 64; off <<= 1) {
        mn = fminf(mn, __shfl_xor(mn, off, 64));
        mx = fmaxf(mx, __shfl_xor(mx, off, 64));
    }
    const bool hasP = (mn < 1e30f);
    const bool hasN = (mx > -1e30f);
    const float tP = hasP ? mn : 0.2f;   // pos_thr fallback
    const float tN = hasN ? mx : 0.8f;   // neg_thr fallback

    // Sparse mined-pair sums: walk set bits only. Low byte = pos candidates,
    // high byte = hot-neg candidates for this j-chunk. k&7 = element index e;
    // dynamic extract via cndmask on the two 64-bit halves (no scratch).
    float ps = 0.f, ns = 0.f;
#pragma unroll
    for (int j = 0; j < 8; ++j) {
        unsigned bm = (unsigned)((mpos >> (j * 8)) & 0xFFull)
                    | ((unsigned)((mneg >> (j * 8)) & 0xFFull) << 8);
        while (bm) {
            const int k = __builtin_ctz(bm);
            bm &= bm - 1;
            const uint64_t h = (k & 4) ? q[j][1] : q[j][0];
            const float s = bf2f((unsigned short)(h >> ((k & 3) * 16)));
            const bool isneg = k >= 8;
            const bool ok  = isneg ? (s + MARGIN > tP) : (s - MARGIN < tN);
            const float a  = isneg ? 40.0f * (s - THRESH) : -2.0f * (s - THRESH);
            const float v  = ok ? __expf(a) : 0.f;
            if (isneg) ns += v; else ps += v;
        }
    }
#pragma unroll
    for (int off = 1; off < 64; off <<= 1) {
        ps += __shfl_xor(ps, off, 64);
        ns += __shfl_xor(ns, off, 64);
    }
    // wave-uniform validity: exists mined pos <=> hasP && mn-M < tN;
    // exists mined neg <=> hasN && mx+M > tP (exact, since mn/mx are exact).
    const bool vP = hasP && (mn - MARGIN < tN);
    const bool vN = hasN && (mx + MARGIN > tP);
    float wsum = 0.f;
    if (lane == 0 && vP && vN && row < lim)
        wsum = 0.5f * log1pf(ps) + 0.025f * log1pf(ns);

    if (lane == 0) bsum[w] = wsum;
    __syncthreads();
    if (t == 0)
        atomicAdd(out, (bsum[0] + bsum[1] + bsum[2] + bsum[3]) * (1.0f / (float)BN));
}

extern "C" void kernel_launch(void* const* d_in, const int* in_sizes, int n_in,
                              void* d_out, int out_size, void* d_ws, size_t ws_size,
                              hipStream_t stream)
{
    const float* feats     = (const float*)d_in[0];
    const int*   labels    = (const int*)d_in[1];
    const int*   label_num = (const int*)d_in[2];
    float*       out       = (float*)d_out;

    char* ws = (char*)d_ws;
    unsigned char*  Fb   = (unsigned char*)ws;                         // 2 MB fp8 feats
    unsigned short* simb = (unsigned short*)(ws + 4u * 1024u * 1024u); // 32 MB bf16 sim

    cvt_kernel<<<2048, 256, 0, stream>>>((const float4*)feats, (uchar4*)Fb, out);

    ms_gemm<<<528, 256, 0, stream>>>(Fb, simb);   // upper-triangle tiles only

    ms_rows<<<1024, 256, 0, stream>>>(simb, labels, label_num, out);
}

// Round 4
// 102.060 us; speedup vs baseline: 1.1453x; 1.1453x over previous
//
#include <hip/hip_runtime.h>
#include <stdint.h>

#define BN 4096
#define DK 512
#define THRESH 0.5f
#define MARGIN 0.1f

typedef __attribute__((ext_vector_type(4)))  int   i32x4;
typedef __attribute__((ext_vector_type(8)))  int   i32x8;
typedef __attribute__((ext_vector_type(16))) float f32x16;
typedef __attribute__((ext_vector_type(8))) unsigned short ushort8;
typedef __attribute__((ext_vector_type(2))) unsigned long long ulong2_t;

__device__ __forceinline__ unsigned short f2bf(float f) {
    unsigned u = __float_as_uint(f);
    u += 0x7FFFu + ((u >> 16) & 1u);   // RNE
    return (unsigned short)(u >> 16);
}
__device__ __forceinline__ float bf2f(unsigned short b) {
    return __uint_as_float((unsigned)b << 16);
}

// fp32 -> OCP e4m3fn, RNE (software; inputs here are |x| <~ 0.5 so the
// clamp/NaN paths are never hot). Subnormal: m = round(a * 2^9).
__device__ __forceinline__ unsigned char f2fp8(float x) {
    float a = fabsf(x);
    unsigned s = (__float_as_uint(x) >> 24) & 0x80u;
    if (a >= 448.f) return (unsigned char)(s | 0x7E);      // clamp to max finite
    if (a < 0.015625f) {                                    // < 2^-6: subnormal
        int m = (int)(a * 512.0f + 0.5f);                   // 0..8 (8 == 2^-6 normal)
        return (unsigned char)(s | m);
    }
    unsigned u = __float_as_uint(a);
    u += 0x0FFFFFu + ((u >> 20) & 1u);                      // RNE into 3-bit mantissa
    unsigned e = (u >> 23) - 127u + 7u;
    unsigned m = (u >> 20) & 7u;
    if (e >= 16u) return (unsigned char)(s | 0x7E);
    return (unsigned char)(s | (e << 3) | m);
}

__device__ __forceinline__ void async_cp16(void* lds, const void* g) {
    __builtin_amdgcn_global_load_lds(
        (const __attribute__((address_space(1))) void*)g,
        (__attribute__((address_space(3))) void*)lds,
        16, 0, 0);
}

// feats fp32 -> fp8 e4m3 (for MFMA); block 0 thread 0 zero-inits out[0]
// (harness re-poisons d_out to 0xAA before every timed replay).
__global__ void cvt_kernel(const float4* __restrict__ in, uchar4* __restrict__ out,
                           float* __restrict__ loss_out) {
    int i = blockIdx.x * blockDim.x + threadIdx.x;   // 524288 threads, 4 elems each
    float4 v = in[i];
    uchar4 o;
    o.x = f2fp8(v.x); o.y = f2fp8(v.y); o.z = f2fp8(v.z); o.w = f2fp8(v.w);
    out[i] = o;
    if (blockIdx.x == 0 && threadIdx.x == 0) loss_out[0] = 0.f;
}

// Triangular GEMM, fp8 inputs: sim = F8 @ F8^T (fp32 accumulate), bf16 store.
// 528 upper-triangle 128x128 tiles; off-diagonal blocks mirror-store C^T via
// an LDS round-trip.
//
// Structure = R1's proven single-buffer 2-barrier K-pipeline (4 slices of
// BK=128B, coalesced global_load_lds with gather-side XOR swizzle, linear LDS
// dest, __syncthreads() only — no hand-rolled sync after the R3 container
// failure). Compute = R2's hardware-verified mfma_scale_f32_32x32x64_f8f6f4
// (scales 0x7F = 2^0, exact fp8) at 2x the 16x16x32 fp8 rate. Fragment read:
// 2x ds_read_b128/lane at physical chunk u^(r&7) — 32 contiguous logical
// k-bytes per lane (lane&31 = row, lane>>5 = k-half), the layout R2 verified.
__global__ __launch_bounds__(256, 4) void ms_gemm(
    const unsigned char* __restrict__ Fb,   // fp8 e4m3 [4096][512] row-major
    unsigned short* __restrict__ simb)      // bf16 bits [4096][4096]
{
    __shared__ __align__(16) unsigned char SMEMB[32768];  // 16K As | 16K Bs
    unsigned char* As = SMEMB;
    unsigned char* Bs = SMEMB + 16384;
    unsigned short* SMEM = (unsigned short*)SMEMB;        // 128x128 bf16 mirror reuse

    const int t    = threadIdx.x;
    const int lane = t & 63;
    const int w    = t >> 6;
    const int wr   = w >> 1, wc = w & 1;
    const int l31  = lane & 31;
    const int kh   = lane >> 5;          // k-half within K=64

    // map linear block id -> upper-triangle tile (by <= bx), 528 blocks
    int l = blockIdx.x, by = 0;
    while (l >= 32 - by) { l -= (32 - by); ++by; }
    const int bx = by + l;
    const int rowBase = by * 128;
    const int colBase = bx * 128;
    const bool diag = (by == bx);

    f32x16 acc[2][2];
#pragma unroll
    for (int i = 0; i < 2; ++i)
#pragma unroll
        for (int j = 0; j < 2; ++j)
#pragma unroll
            for (int e = 0; e < 16; ++e) acc[i][j][e] = 0.f;

    for (int k0 = 0; k0 < DK; k0 += 128) {   // 4 iterations (BK=128 bytes)
#pragma unroll
        for (int it = 0; it < 4; ++it) {
            const int id = it * 256 + t;          // 0..1023
            const int r  = id >> 3;               // staging row 0..127
            const int gc = (id & 7) ^ (r & 7);    // XOR-swizzled 16B chunk
            async_cp16(As + id * 16,
                       Fb + (size_t)(rowBase + r) * DK + k0 + gc * 16);
        }
#pragma unroll
        for (int it = 0; it < 4; ++it) {          // diag blocks stage B
            const int id = it * 256 + t;          // redundantly (32/528) —
            const int r  = id >> 3;               // one code path
            const int gc = (id & 7) ^ (r & 7);
            async_cp16(Bs + id * 16,
                       Fb + (size_t)(colBase + r) * DK + k0 + gc * 16);
        }
        __syncthreads();   // compiler drains vmcnt before s_barrier

#pragma unroll
        for (int ks = 0; ks < 2; ++ks) {          // 2 x (K=64) per slice
            i32x8 af[2], bg[2];
#pragma unroll
            for (int im = 0; im < 2; ++im) {
                const int r  = wr * 64 + im * 32 + l31;
                const int u0 = ks * 4 + kh * 2;            // logical 16B chunk
                const int p0 = u0 ^ (r & 7);
                const int p1 = (u0 + 1) ^ (r & 7);
                i32x4 lo = *reinterpret_cast<const i32x4*>(&As[r * 128 + p0 * 16]);
                i32x4 hi = *reinterpret_cast<const i32x4*>(&As[r * 128 + p1 * 16]);
                af[im] = __builtin_shufflevector(lo, hi, 0, 1, 2, 3, 4, 5, 6, 7);
            }
#pragma unroll
            for (int jn = 0; jn < 2; ++jn) {
                const int c  = wc * 64 + jn * 32 + l31;
                const int u0 = ks * 4 + kh * 2;
                const int p0 = u0 ^ (c & 7);
                const int p1 = (u0 + 1) ^ (c & 7);
                i32x4 lo = *reinterpret_cast<const i32x4*>(&Bs[c * 128 + p0 * 16]);
                i32x4 hi = *reinterpret_cast<const i32x4*>(&Bs[c * 128 + p1 * 16]);
                bg[jn] = __builtin_shufflevector(lo, hi, 0, 1, 2, 3, 4, 5, 6, 7);
            }
#pragma unroll
            for (int im = 0; im < 2; ++im)
#pragma unroll
                for (int jn = 0; jn < 2; ++jn)
                    acc[im][jn] = __builtin_amdgcn_mfma_scale_f32_32x32x64_f8f6f4(
                        af[im], bg[jn], acc[im][jn],
                        0, 0,                       // cbsz/blgp = FP8 e4m3
                        0, 0x7F7F7F7F,              // scale A = 2^0 (exact)
                        0, 0x7F7F7F7F);             // scale B = 2^0 (exact)
        }
        __syncthreads();   // last iteration: also guards SMEM reuse below
    }

    // Direct store. C/D layout (32x32): col=lane&31, row=(reg&3)+8*(reg>>2)+4*kh.
#pragma unroll
    for (int im = 0; im < 2; ++im)
#pragma unroll
        for (int g = 0; g < 4; ++g)
#pragma unroll
            for (int rg = 0; rg < 4; ++rg) {
                const int grow = rowBase + wr * 64 + im * 32 + g * 8 + kh * 4 + rg;
                unsigned short* dst = simb + (size_t)grow * BN + colBase + wc * 64 + l31;
#pragma unroll
                for (int jn = 0; jn < 2; ++jn)
                    dst[jn * 32] = f2bf(acc[im][jn][g * 4 + rg]);
            }

    if (diag) return;

    // Mirror store: write C^T into SMEM (phys 16B-chunk XOR-swizzled by column),
    // then read rows of C^T and store 16B-coalesced to sim[col][row].
    // acc regs g*4+0..3 are rows r..r+3 (r = im*32+g*8+kh*4, so r&7 in {0,4}).
#pragma unroll
    for (int im = 0; im < 2; ++im)
#pragma unroll
        for (int jn = 0; jn < 2; ++jn)
#pragma unroll
            for (int g = 0; g < 4; ++g) {
                ushort4 v;
                v.x = f2bf(acc[im][jn][g * 4 + 0]);
                v.y = f2bf(acc[im][jn][g * 4 + 1]);
                v.z = f2bf(acc[im][jn][g * 4 + 2]);
                v.w = f2bf(acc[im][jn][g * 4 + 3]);
                const int c  = wc * 64 + jn * 32 + l31;            // tile col
                const int r  = wr * 64 + im * 32 + g * 8 + kh * 4; // tile row
                const int r8 = r >> 3;                             // 16B chunk 0..15
                const int ri = r & 7;                              // 0 or 4
                *reinterpret_cast<ushort4*>(
                    &SMEM[c * 128 + ((r8 ^ (c & 15)) << 3) + ri]) = v;
            }
    __syncthreads();

    const int lch = t & 7;    // low 16B chunk of the transposed row
    const int trw = t >> 3;   // 0..31
#pragma unroll
    for (int it = 0; it < 4; ++it) {
        const int tr = it * 32 + trw;                      // transposed row = orig col
        const int q1 = lch ^ (tr & 15);
        const int q2 = (lch + 8) ^ (tr & 15);
        ushort8 a = *reinterpret_cast<const ushort8*>(&SMEM[tr * 128 + q1 * 8]);
        ushort8 b = *reinterpret_cast<const ushort8*>(&SMEM[tr * 128 + q2 * 8]);
        unsigned short* dst = simb + (size_t)(colBase + tr) * BN + rowBase;
        *reinterpret_cast<ushort8*>(&dst[lch * 8])       = a;
        *reinterpret_cast<ushort8*>(&dst[(lch + 8) * 8]) = b;
    }
}

// Per-row pass: one wave owns one full row (held in 32 VGPRs), so the row's
// min/max thresholds are wave-local. 1024 blocks x 4 waves x 1 row.
// Labels staged transposed in LDS (conflict-free per-(j,e) reads).
//
// Pass 1 builds, per lane: running min over pos / max over neg, plus two
// 64-bit candidate masks: mpos (pos pairs) and mneg (!same && s > 0.125 —
// the numeric neg cutoff; dropped terms are each < e^-15, Dloss <= 3.1e-5).
// Pass 2 walks ONLY the set bits (~8 pos + ~10 hot-neg per ROW) instead of a
// dense 64-iteration scan. Validity is wave-uniform: exists neg with
// s+M > tP <=> hasNeg && mx+M > tP (mx exact max over ALL negs); same for pos.
__global__ __launch_bounds__(256) void ms_rows(
    const unsigned short* __restrict__ simb,
    const int* __restrict__ labels,
    const int* __restrict__ label_num,
    float* __restrict__ out)
{
    __shared__ int   labT[8][512];   // 16 KB, labT[i&7][i>>3] = labels[i]
    __shared__ float bsum[4];

    const int t    = threadIdx.x;
    const int lane = t & 63;
    const int w    = t >> 6;

    for (int i = t; i < BN; i += 256) labT[i & 7][i >> 3] = labels[i];
    __syncthreads();

    const int lim = BN - label_num[0];
    const int row = blockIdx.x * 4 + w;
    const int lr  = labT[row & 7][row >> 3];
    const ulong2_t* rq = (const ulong2_t*)(simb + (size_t)row * BN);

    ulong2_t q[8];                    // full row: 8 x 16B per lane (32 VGPRs)
    uint64_t mpos = 0, mneg = 0;
    float mn = INFINITY, mx = -INFINITY;
#pragma unroll
    for (int j = 0; j < 8; ++j) {
        q[j] = rq[j * 64 + lane];
        const int c8 = j * 64 + lane;            // col>>3 for this lane's 8 elems
#pragma unroll
        for (int e = 0; e < 8; ++e) {
            const int col = c8 * 8 + e;
            const float s = bf2f((unsigned short)(q[j][e >> 2] >> ((e & 3) * 16)));
            const bool same = (labT[e][c8] == lr);   // conflict-free LDS read
            const bool pos  = same && (col != row);
            if (pos)   mn = fminf(mn, s);
            if (!same) mx = fmaxf(mx, s);
            mpos |= (uint64_t)pos << (j * 8 + e);
            mneg |= (uint64_t)(!same && (s > 0.125f)) << (j * 8 + e);
        }
    }
#pragma unroll
    for (int off = 1; off < 64; off <<= 1) {
        mn = fminf(mn, __shfl_xor(mn, off, 64));
        mx = fmaxf(mx, __shfl_xor(mx, off, 64));
    }
    const bool hasP = (mn < 1e30f);
    const bool hasN = (mx > -1e30f);
    const float tP = hasP ? mn : 0.2f;   // pos_thr fallback
    const float tN = hasN ? mx : 0.8f;   // neg_thr fallback

    // Sparse mined-pair sums: walk set bits only. Low byte = pos candidates,
    // high byte = hot-neg candidates for this j-chunk. k&7 = element index e;
    // dynamic extract via cndmask on the two 64-bit halves (no scratch).
    float ps = 0.f, ns = 0.f;
#pragma unroll
    for (int j = 0; j < 8; ++j) {
        unsigned bm = (unsigned)((mpos >> (j * 8)) & 0xFFull)
                    | ((unsigned)((mneg >> (j * 8)) & 0xFFull) << 8);
        while (bm) {
            const int k = __builtin_ctz(bm);
            bm &= bm - 1;
            const uint64_t h = (k & 4) ? q[j][1] : q[j][0];
            const float s = bf2f((unsigned short)(h >> ((k & 3) * 16)));
            const bool isneg = k >= 8;
            const bool ok  = isneg ? (s + MARGIN > tP) : (s - MARGIN < tN);
            const float a  = isneg ? 40.0f * (s - THRESH) : -2.0f * (s - THRESH);
            const float v  = ok ? __expf(a) : 0.f;
            if (isneg) ns += v; else ps += v;
        }
    }
#pragma unroll
    for (int off = 1; off < 64; off <<= 1) {
        ps += __shfl_xor(ps, off, 64);
        ns += __shfl_xor(ns, off, 64);
    }
    // wave-uniform validity: exists mined pos <=> hasP && mn-M < tN;
    // exists mined neg <=> hasN && mx+M > tP (exact, since mn/mx are exact).
    const bool vP = hasP && (mn - MARGIN < tN);
    const bool vN = hasN && (mx + MARGIN > tP);
    float wsum = 0.f;
    if (lane == 0 && vP && vN && row < lim)
        wsum = 0.5f * log1pf(ps) + 0.025f * log1pf(ns);

    if (lane == 0) bsum[w] = wsum;
    __syncthreads();
    if (t == 0)
        atomicAdd(out, (bsum[0] + bsum[1] + bsum[2] + bsum[3]) * (1.0f / (float)BN));
}

extern "C" void kernel_launch(void* const* d_in, const int* in_sizes, int n_in,
                              void* d_out, int out_size, void* d_ws, size_t ws_size,
                              hipStream_t stream)
{
    const float* feats     = (const float*)d_in[0];
    const int*   labels    = (const int*)d_in[1];
    const int*   label_num = (const int*)d_in[2];
    float*       out       = (float*)d_out;

    char* ws = (char*)d_ws;
    unsigned char*  Fb   = (unsigned char*)ws;                         // 2 MB fp8 feats
    unsigned short* simb = (unsigned short*)(ws + 4u * 1024u * 1024u); // 32 MB bf16 sim

    cvt_kernel<<<2048, 256, 0, stream>>>((const float4*)feats, (uchar4*)Fb, out);

    ms_gemm<<<528, 256, 0, stream>>>(Fb, simb);   // upper-triangle tiles only

    ms_rows<<<1024, 256, 0, stream>>>(simb, labels, label_num, out);
}